// Round 12
// baseline (843.959 us; speedup 1.0000x reference)
//
#include <hip/hip_runtime.h>
#include <math.h>

typedef __attribute__((ext_vector_type(8))) short bf16x8;
typedef __attribute__((ext_vector_type(4))) float f32x4;

#define NBLK 2048   // scatter/hist blocks (8 blocks/CU)
#define GB   16     // b-groups for column prefix
#define BPG  (NBLK / GB)

// ---------------- bf16 helpers (RNE) ----------------

__device__ __forceinline__ unsigned short f2b(float f) {
  unsigned u = __float_as_uint(f);
  unsigned r = u + 0x7fffu + ((u >> 16) & 1u);
  return (unsigned short)(r >> 16);
}
__device__ __forceinline__ float b2f_lo(unsigned v) {
  return __uint_as_float(v << 16);
}
__device__ __forceinline__ float b2f_hi(unsigned v) {
  return __uint_as_float(v & 0xffff0000u);
}

// ================= bucket-sort CSR build (no global atomics) =================
// bucket k covers dst in [k*64, k*64+64); all edges of a node share one bucket.

__global__ __launch_bounds__(256) void bucket_hist(const int* __restrict__ dst,
                                                   int* __restrict__ blkhist,
                                                   int NB, int E, int chunk) {
  extern __shared__ int sm_hist[];
  for (int i = threadIdx.x; i < NB; i += 256) sm_hist[i] = 0;
  __syncthreads();
  const int b = blockIdx.x;
  const int beg = b * chunk;
  const int end = min(E, beg + chunk);
  int j = beg + threadIdx.x;
  for (; j + 768 < end; j += 1024) {  // 4 independent loads in flight
    const int d0 = dst[j], d1 = dst[j + 256], d2 = dst[j + 512], d3 = dst[j + 768];
    atomicAdd(&sm_hist[d0 >> 6], 1);
    atomicAdd(&sm_hist[d1 >> 6], 1);
    atomicAdd(&sm_hist[d2 >> 6], 1);
    atomicAdd(&sm_hist[d3 >> 6], 1);
  }
  for (; j < end; j += 256) atomicAdd(&sm_hist[dst[j] >> 6], 1);
  __syncthreads();
  for (int i = threadIdx.x; i < NB; i += 256) blkhist[(long)b * NB + i] = sm_hist[i];
}

// ---- 3-phase coalesced column prefix over blkhist[b][k] ----
// phase 1: per-(group, column) partial sums (coalesced over k)
__global__ __launch_bounds__(256) void col_part(const int* __restrict__ blkhist,
                                                int* __restrict__ partials, int NB) {
  const int k = blockIdx.x * 256 + threadIdx.x;
  const int g = blockIdx.y;
  if (k >= NB) return;
  const long base = (long)g * BPG * NB + k;
  int sum = 0;
  int i = 0;
  for (; i + 4 <= BPG; i += 4) {
    const int t0 = blkhist[base + (long)(i + 0) * NB];
    const int t1 = blkhist[base + (long)(i + 1) * NB];
    const int t2 = blkhist[base + (long)(i + 2) * NB];
    const int t3 = blkhist[base + (long)(i + 3) * NB];
    sum += t0 + t1 + t2 + t3;
  }
  for (; i < BPG; ++i) sum += blkhist[base + (long)i * NB];
  partials[(long)g * NB + k] = sum;
}

// phase 2: exclusive scan over the GB groups per column; bstart[k] = column total
__global__ __launch_bounds__(256) void col_scan16(int* __restrict__ partials,
                                                  int* __restrict__ bstart, int NB) {
  const int k = blockIdx.x * 256 + threadIdx.x;
  if (k >= NB) return;
  int run = 0;
#pragma unroll
  for (int g = 0; g < GB; ++g) {
    const int t = partials[(long)g * NB + k];
    partials[(long)g * NB + k] = run;
    run += t;
  }
  bstart[k] = run;
}

// phase 3: within-group exclusive prefix + group base (coalesced over k)
__global__ __launch_bounds__(256) void col_apply(int* __restrict__ blkhist,
                                                 const int* __restrict__ partials,
                                                 int NB) {
  const int k = blockIdx.x * 256 + threadIdx.x;
  const int g = blockIdx.y;
  if (k >= NB) return;
  const long base = (long)g * BPG * NB + k;
  int run = partials[(long)g * NB + k];
  int i = 0;
  for (; i + 4 <= BPG; i += 4) {
    const int t0 = blkhist[base + (long)(i + 0) * NB];
    const int t1 = blkhist[base + (long)(i + 1) * NB];
    const int t2 = blkhist[base + (long)(i + 2) * NB];
    const int t3 = blkhist[base + (long)(i + 3) * NB];
    blkhist[base + (long)(i + 0) * NB] = run; run += t0;
    blkhist[base + (long)(i + 1) * NB] = run; run += t1;
    blkhist[base + (long)(i + 2) * NB] = run; run += t2;
    blkhist[base + (long)(i + 3) * NB] = run; run += t3;
  }
  for (; i < BPG; ++i) {
    const int t = blkhist[base + (long)i * NB];
    blkhist[base + (long)i * NB] = run;
    run += t;
  }
}

// single-block in-place exclusive scan over cr[0..n); cr[n] = total.
__global__ __launch_bounds__(256) void scan_single(int* __restrict__ cr, int n) {
  __shared__ int sm[256];
  __shared__ int sbase;
  if (threadIdx.x == 0) sbase = 0;
  __syncthreads();
  for (int c0 = 0; c0 < n; c0 += 256) {
    const int i = c0 + threadIdx.x;
    const int v = (i < n) ? cr[i] : 0;
    sm[threadIdx.x] = v;
    __syncthreads();
    for (int off = 1; off < 256; off <<= 1) {
      int a = (threadIdx.x >= off) ? sm[threadIdx.x - off] : 0;
      __syncthreads();
      sm[threadIdx.x] += a;
      __syncthreads();
    }
    const int b = sbase;
    const int tot = sm[255];
    if (i < n) cr[i] = b + sm[threadIdx.x] - v;
    __syncthreads();
    if (threadIdx.x == 0) sbase = b + tot;
    __syncthreads();
  }
  if (threadIdx.x == 0) cr[n] = sbase;
}

// scatter edges into bucket ranges; positions via LDS cursors (no global atomics)
__global__ __launch_bounds__(256) void bucket_scatter(const int* __restrict__ src,
                                                      const int* __restrict__ dst,
                                                      const float* __restrict__ ew,
                                                      const int* __restrict__ blkhist,
                                                      const int* __restrict__ bstart,
                                                      uint2* __restrict__ bkt, int NB,
                                                      int E, int chunk) {
  extern __shared__ int sm_cur[];
  const int b = blockIdx.x;
  for (int i = threadIdx.x; i < NB; i += 256)
    sm_cur[i] = blkhist[(long)b * NB + i] + bstart[i];
  __syncthreads();
  const int beg = b * chunk;
  const int end = min(E, beg + chunk);
  int j = beg + threadIdx.x;
  for (; j + 768 < end; j += 1024) {  // 4 edges in flight
    const int d0 = dst[j], d1 = dst[j + 256], d2 = dst[j + 512], d3 = dst[j + 768];
    const int s0 = src[j], s1 = src[j + 256], s2 = src[j + 512], s3 = src[j + 768];
    const float e0 = ew[j], e1 = ew[j + 256], e2 = ew[j + 512], e3 = ew[j + 768];
    int q0 = (int)(e0 * 32767.f + 0.5f); q0 = (q0 < 0) ? 0 : ((q0 > 32767) ? 32767 : q0);
    int q1 = (int)(e1 * 32767.f + 0.5f); q1 = (q1 < 0) ? 0 : ((q1 > 32767) ? 32767 : q1);
    int q2 = (int)(e2 * 32767.f + 0.5f); q2 = (q2 < 0) ? 0 : ((q2 > 32767) ? 32767 : q2);
    int q3 = (int)(e3 * 32767.f + 0.5f); q3 = (q3 < 0) ? 0 : ((q3 > 32767) ? 32767 : q3);
    const int p0 = atomicAdd(&sm_cur[d0 >> 6], 1);
    bkt[p0] = make_uint2(((unsigned)s0 << 15) | (unsigned)q0, (unsigned)(d0 & 63));
    const int p1 = atomicAdd(&sm_cur[d1 >> 6], 1);
    bkt[p1] = make_uint2(((unsigned)s1 << 15) | (unsigned)q1, (unsigned)(d1 & 63));
    const int p2 = atomicAdd(&sm_cur[d2 >> 6], 1);
    bkt[p2] = make_uint2(((unsigned)s2 << 15) | (unsigned)q2, (unsigned)(d2 & 63));
    const int p3 = atomicAdd(&sm_cur[d3 >> 6], 1);
    bkt[p3] = make_uint2(((unsigned)s3 << 15) | (unsigned)q3, (unsigned)(d3 & 63));
  }
  for (; j < end; j += 256) {
    const int d = dst[j];
    int q = (int)(ew[j] * 32767.f + 0.5f);
    q = (q < 0) ? 0 : ((q > 32767) ? 32767 : q);
    const unsigned rec = ((unsigned)src[j] << 15) | (unsigned)q;
    const int pos = atomicAdd(&sm_cur[d >> 6], 1);
    bkt[pos] = make_uint2(rec, (unsigned)(d & 63));
  }
}

// per-bucket: local 64-node CSR + row_start + deg/dinv, then scatter recs
__global__ __launch_bounds__(256) void bucket_finalize(const uint2* __restrict__ bkt,
                                                       const int* __restrict__ bstart,
                                                       unsigned* __restrict__ recs,
                                                       int* __restrict__ row_start,
                                                       float* __restrict__ dinv, int NB,
                                                       int N, int E) {
  __shared__ int hist[64], qs[64], cur[64], lstart[64];
  const int k = blockIdx.x;
  const int t = threadIdx.x;
  if (t < 64) { hist[t] = 0; qs[t] = 0; }
  __syncthreads();
  const int beg = bstart[k], end = bstart[k + 1];
  for (int j = beg + t; j < end; j += 256) {
    const uint2 v = bkt[j];
    atomicAdd(&hist[v.y], 1);
    atomicAdd(&qs[v.y], (int)(v.x & 32767u));
  }
  __syncthreads();
  if (t == 0) {
    int run = 0;
    for (int i = 0; i < 64; ++i) { lstart[i] = run; run += hist[i]; }
  }
  __syncthreads();
  if (t < 64) {
    cur[t] = lstart[t];
    const int node = k * 64 + t;
    if (node < N) {
      row_start[node] = beg + lstart[t];
      dinv[node] = rsqrtf((float)qs[t] * (1.f / 32767.f) + 2.0f);  // +2 self-loop
    }
  }
  if (k == NB - 1 && t == 0) row_start[N] = E;
  __syncthreads();
  for (int j = beg + t; j < end; j += 256) {
    const uint2 v = bkt[j];
    const int off = atomicAdd(&cur[v.y], 1);  // LDS atomic
    recs[beg + off] = v.x;
  }
}

// ---------------- fold dinv[src] into records: q' = q15( ew*dinv[src] / 0.75 ) ----------------

__global__ __launch_bounds__(256) void fold_dinv(unsigned int* __restrict__ recs,
                                                 const float* __restrict__ dinv, int E) {
  int i = blockIdx.x * 256 + threadIdx.x;
  if (i >= E) return;
  const unsigned rec = recs[i];
  const int s = rec >> 15;
  const float v = (float)(rec & 32767u) * (1.f / 32767.f) * dinv[s];
  int q = (int)(v * (32767.f / 0.75f) + 0.5f);
  q = (q > 32767) ? 32767 : q;
  recs[i] = ((unsigned)s << 15) | (unsigned)q;
}

// ---------------- x (f32) -> xb (bf16), 8 elements/thread ----------------

__global__ __launch_bounds__(256) void to_bf16_8(const float* __restrict__ x,
                                                 unsigned short* __restrict__ xb,
                                                 int n8) {
  int i = blockIdx.x * 256 + threadIdx.x;
  if (i >= n8) return;
  const float4 a = *(const float4*)&x[(long)i * 8];
  const float4 b = *(const float4*)&x[(long)i * 8 + 4];
  uint4 o;
  o.x = (unsigned)f2b(a.x) | ((unsigned)f2b(a.y) << 16);
  o.y = (unsigned)f2b(a.z) | ((unsigned)f2b(a.w) << 16);
  o.z = (unsigned)f2b(b.x) | ((unsigned)f2b(b.y) << 16);
  o.w = (unsigned)f2b(b.z) | ((unsigned)f2b(b.w) << 16);
  *(uint4*)&xb[(long)i * 8] = o;
}

// pack W (f32, row-major [K][C]) into per-lane MFMA B-fragments (bf16)
__global__ __launch_bounds__(256) void pack_wfrag(const float* __restrict__ W,
                                                  unsigned short* __restrict__ frag,
                                                  int C, int total) {
  int i = blockIdx.x * 256 + threadIdx.x;
  if (i >= total) return;
  const int e = i & 7;
  const int lane = (i >> 3) & 63;
  const int t = i >> 9;  // ct*(K/32) + kk, K/32 == 4
  const int kk = t & 3;
  const int ct = t >> 2;
  const int k = kk * 32 + (lane >> 4) * 8 + e;
  const int c = ct * 16 + (lane & 15);
  frag[i] = f2b(W[(long)k * C + c]);
}

// ---------------- layer-1 gather, 16-col pass: 2 lanes/node, uint4, 8x unrolled ----------------
// pass covers uint4 slots {slot, slot+1} of the 16-slot row. Per-pass random pool
// = 3.2 MB < 4 MB per-XCD L2 -> near-resident.

__global__ __launch_bounds__(256) void gather_l1_pass(const uint4* __restrict__ xb4,
                                                      const unsigned int* __restrict__ recs,
                                                      const int* __restrict__ row_start,
                                                      const float* __restrict__ dinv,
                                                      uint4* __restrict__ xab4, int N,
                                                      int slot) {
  const int t = blockIdx.x * 256 + threadIdx.x;
  const int d = t >> 1;
  if (d >= N) return;
  const int jl = slot + (t & 1);
  const int beg = row_start[d], end = row_start[d + 1];
  const float dd = dinv[d];
  constexpr float S = 0.75f / 32767.f;
  const uint4 sv = xb4[(long)d * 16 + jl];
  const float sl = 2.f * dd * dd;
  float acc[8];
  acc[0] = b2f_lo(sv.x) * sl; acc[1] = b2f_hi(sv.x) * sl;
  acc[2] = b2f_lo(sv.y) * sl; acc[3] = b2f_hi(sv.y) * sl;
  acc[4] = b2f_lo(sv.z) * sl; acc[5] = b2f_hi(sv.z) * sl;
  acc[6] = b2f_lo(sv.w) * sl; acc[7] = b2f_hi(sv.w) * sl;
  int j = beg;
  for (; j + 8 <= end; j += 8) {
    unsigned rr[8];
    uint4 vv[8];
#pragma unroll
    for (int u = 0; u < 8; ++u) rr[u] = recs[j + u];
#pragma unroll
    for (int u = 0; u < 8; ++u) vv[u] = xb4[(long)(rr[u] >> 15) * 16 + jl];
#pragma unroll
    for (int u = 0; u < 8; ++u) {
      const float cf = (float)(rr[u] & 32767u) * S * dd;
      acc[0] = fmaf(cf, b2f_lo(vv[u].x), acc[0]);
      acc[1] = fmaf(cf, b2f_hi(vv[u].x), acc[1]);
      acc[2] = fmaf(cf, b2f_lo(vv[u].y), acc[2]);
      acc[3] = fmaf(cf, b2f_hi(vv[u].y), acc[3]);
      acc[4] = fmaf(cf, b2f_lo(vv[u].z), acc[4]);
      acc[5] = fmaf(cf, b2f_hi(vv[u].z), acc[5]);
      acc[6] = fmaf(cf, b2f_lo(vv[u].w), acc[6]);
      acc[7] = fmaf(cf, b2f_hi(vv[u].w), acc[7]);
    }
  }
  for (; j < end; ++j) {
    const unsigned rec = recs[j];
    const uint4 v = xb4[(long)(rec >> 15) * 16 + jl];
    const float cf = (float)(rec & 32767u) * S * dd;
    acc[0] = fmaf(cf, b2f_lo(v.x), acc[0]);
    acc[1] = fmaf(cf, b2f_hi(v.x), acc[1]);
    acc[2] = fmaf(cf, b2f_lo(v.y), acc[2]);
    acc[3] = fmaf(cf, b2f_hi(v.y), acc[3]);
    acc[4] = fmaf(cf, b2f_lo(v.z), acc[4]);
    acc[5] = fmaf(cf, b2f_hi(v.z), acc[5]);
    acc[6] = fmaf(cf, b2f_lo(v.w), acc[6]);
    acc[7] = fmaf(cf, b2f_hi(v.w), acc[7]);
  }
  uint4 o;
  o.x = (unsigned)f2b(acc[0]) | ((unsigned)f2b(acc[1]) << 16);
  o.y = (unsigned)f2b(acc[2]) | ((unsigned)f2b(acc[3]) << 16);
  o.z = (unsigned)f2b(acc[4]) | ((unsigned)f2b(acc[5]) << 16);
  o.w = (unsigned)f2b(acc[6]) | ((unsigned)f2b(acc[7]) << 16);
  xab4[(long)d * 16 + jl] = o;
}

// ---------------- fused MLP via MFMA (verified layout, unchanged) ----------------

__global__ __launch_bounds__(256) void fused_mlp_mfma(
    const unsigned short* __restrict__ xab, const unsigned short* __restrict__ w0f,
    const float* __restrict__ b0, const unsigned short* __restrict__ w1f,
    unsigned short* __restrict__ r2b, int N) {
  __shared__ unsigned short Hl[4][16][136];
  const int tid = threadIdx.x;
  const int w = tid >> 6, l = tid & 63;
  const int lr = l & 15, lg = l >> 4;
  const int row0 = blockIdx.x * 64 + w * 16;

  int arow = row0 + lr;
  if (arow >= N) arow = N - 1;
  const unsigned short* ap = xab + (long)arow * 128 + lg * 8;
  const bf16x8 a0 = *(const bf16x8*)(ap);
  const bf16x8 a1 = *(const bf16x8*)(ap + 32);
  const bf16x8 a2 = *(const bf16x8*)(ap + 64);
  const bf16x8 a3 = *(const bf16x8*)(ap + 96);

  for (int ct = 0; ct < 8; ++ct) {
    const unsigned short* bp = w0f + ct * 2048 + l * 8;
    f32x4 acc = {0.f, 0.f, 0.f, 0.f};
    acc = __builtin_amdgcn_mfma_f32_16x16x32_bf16(a0, *(const bf16x8*)(bp), acc, 0, 0, 0);
    acc = __builtin_amdgcn_mfma_f32_16x16x32_bf16(a1, *(const bf16x8*)(bp + 512), acc, 0, 0, 0);
    acc = __builtin_amdgcn_mfma_f32_16x16x32_bf16(a2, *(const bf16x8*)(bp + 1024), acc, 0, 0, 0);
    acc = __builtin_amdgcn_mfma_f32_16x16x32_bf16(a3, *(const bf16x8*)(bp + 1536), acc, 0, 0, 0);
    const float bv = b0[ct * 16 + lr];
#pragma unroll
    for (int r = 0; r < 4; ++r) {
      Hl[w][lg * 4 + r][ct * 16 + lr] = f2b(fmaxf(acc[r] + bv, 0.f));
    }
  }

  const unsigned short* hp = &Hl[w][lr][lg * 8];
  const bf16x8 h0 = *(const bf16x8*)(hp);
  const bf16x8 h1 = *(const bf16x8*)(hp + 32);
  const bf16x8 h2 = *(const bf16x8*)(hp + 64);
  const bf16x8 h3 = *(const bf16x8*)(hp + 96);

  for (int ct = 0; ct < 4; ++ct) {
    const unsigned short* bp = w1f + ct * 2048 + l * 8;
    f32x4 acc = {0.f, 0.f, 0.f, 0.f};
    acc = __builtin_amdgcn_mfma_f32_16x16x32_bf16(h0, *(const bf16x8*)(bp), acc, 0, 0, 0);
    acc = __builtin_amdgcn_mfma_f32_16x16x32_bf16(h1, *(const bf16x8*)(bp + 512), acc, 0, 0, 0);
    acc = __builtin_amdgcn_mfma_f32_16x16x32_bf16(h2, *(const bf16x8*)(bp + 1024), acc, 0, 0, 0);
    acc = __builtin_amdgcn_mfma_f32_16x16x32_bf16(h3, *(const bf16x8*)(bp + 1536), acc, 0, 0, 0);
#pragma unroll
    for (int r = 0; r < 4; ++r) {
      const int orow = row0 + lg * 4 + r;
      if (orow < N) r2b[(long)orow * 64 + ct * 16 + lr] = f2b(acc[r]);
    }
  }
}

// ---------------- layer-2 gather, 16-col pass + bias + sigmoid: 2 lanes/node ----------------
// pass covers uint4 slots {slot, slot+1} of the 8-slot row (pool 3.2 MB/pass).

__global__ __launch_bounds__(256) void gather_l2_pass(const uint4* __restrict__ r2b4,
                                                      const unsigned int* __restrict__ recs,
                                                      const int* __restrict__ row_start,
                                                      const float* __restrict__ dinv,
                                                      const float* __restrict__ b1,
                                                      float* __restrict__ out, int N,
                                                      int slot) {
  const int t = blockIdx.x * 256 + threadIdx.x;
  const int d = t >> 1;
  if (d >= N) return;
  const int jl = slot + (t & 1);
  const int beg = row_start[d], end = row_start[d + 1];
  const float dd = dinv[d];
  constexpr float S = 0.75f / 32767.f;
  const uint4 sv = r2b4[(long)d * 8 + jl];
  const float sl = 2.f * dd * dd;
  float acc[8];
  acc[0] = b2f_lo(sv.x) * sl; acc[1] = b2f_hi(sv.x) * sl;
  acc[2] = b2f_lo(sv.y) * sl; acc[3] = b2f_hi(sv.y) * sl;
  acc[4] = b2f_lo(sv.z) * sl; acc[5] = b2f_hi(sv.z) * sl;
  acc[6] = b2f_lo(sv.w) * sl; acc[7] = b2f_hi(sv.w) * sl;
  int j = beg;
  for (; j + 8 <= end; j += 8) {
    unsigned rr[8];
    uint4 vv[8];
#pragma unroll
    for (int u = 0; u < 8; ++u) rr[u] = recs[j + u];
#pragma unroll
    for (int u = 0; u < 8; ++u) vv[u] = r2b4[(long)(rr[u] >> 15) * 8 + jl];
#pragma unroll
    for (int u = 0; u < 8; ++u) {
      const float cf = (float)(rr[u] & 32767u) * S * dd;
      acc[0] = fmaf(cf, b2f_lo(vv[u].x), acc[0]);
      acc[1] = fmaf(cf, b2f_hi(vv[u].x), acc[1]);
      acc[2] = fmaf(cf, b2f_lo(vv[u].y), acc[2]);
      acc[3] = fmaf(cf, b2f_hi(vv[u].y), acc[3]);
      acc[4] = fmaf(cf, b2f_lo(vv[u].z), acc[4]);
      acc[5] = fmaf(cf, b2f_hi(vv[u].z), acc[5]);
      acc[6] = fmaf(cf, b2f_lo(vv[u].w), acc[6]);
      acc[7] = fmaf(cf, b2f_hi(vv[u].w), acc[7]);
    }
  }
  for (; j < end; ++j) {
    const unsigned rec = recs[j];
    const uint4 v = r2b4[(long)(rec >> 15) * 8 + jl];
    const float cf = (float)(rec & 32767u) * S * dd;
    acc[0] = fmaf(cf, b2f_lo(v.x), acc[0]);
    acc[1] = fmaf(cf, b2f_hi(v.x), acc[1]);
    acc[2] = fmaf(cf, b2f_lo(v.y), acc[2]);
    acc[3] = fmaf(cf, b2f_hi(v.y), acc[3]);
    acc[4] = fmaf(cf, b2f_lo(v.z), acc[4]);
    acc[5] = fmaf(cf, b2f_hi(v.z), acc[5]);
    acc[6] = fmaf(cf, b2f_lo(v.w), acc[6]);
    acc[7] = fmaf(cf, b2f_hi(v.w), acc[7]);
  }
  const int c = jl * 8;  // column base within the 64-wide row
  const float4 ba = *(const float4*)&b1[c];
  const float4 bb = *(const float4*)&b1[c + 4];
  float4 o1, o2;
  o1.x = 1.f / (1.f + __expf(-(acc[0] + ba.x)));
  o1.y = 1.f / (1.f + __expf(-(acc[1] + ba.y)));
  o1.z = 1.f / (1.f + __expf(-(acc[2] + ba.z)));
  o1.w = 1.f / (1.f + __expf(-(acc[3] + ba.w)));
  o2.x = 1.f / (1.f + __expf(-(acc[4] + bb.x)));
  o2.y = 1.f / (1.f + __expf(-(acc[5] + bb.y)));
  o2.z = 1.f / (1.f + __expf(-(acc[6] + bb.z)));
  o2.w = 1.f / (1.f + __expf(-(acc[7] + bb.w)));
  *(float4*)&out[(long)d * 64 + c] = o1;
  *(float4*)&out[(long)d * 64 + c + 4] = o2;
}

// ---------------- launch ----------------
// out = sigmoid( Ahat @ (relu((Ahat @ x) @ W0 + b0) @ W1) + b1 ),
// Ahat = D^-1/2 (A+2I) D^-1/2, using Ahat(x W0) == (Ahat x) W0.
// CSR via LDS-histogram bucket sort (zero global atomics), NBLK=2048, 3-phase
// coalesced column prefix; blkhist aliased into xab (disjoint lifetimes);
// gathers split into 16-col passes (3.2 MB pool/pass, per-XCD-L2-resident);
// MLP on matrix cores. Workspace ~65 MB (< 71.6 MB proven available).

extern "C" void kernel_launch(void* const* d_in, const int* in_sizes, int n_in,
                              void* d_out, int out_size, void* d_ws, size_t ws_size,
                              hipStream_t stream) {
  const float* x  = (const float*)d_in[0];
  const int* src  = (const int*)d_in[1];
  const float* ew = (const float*)d_in[2];
  const float* W0 = (const float*)d_in[3];
  const float* b0 = (const float*)d_in[4];
  const float* W1 = (const float*)d_in[5];
  const float* b1 = (const float*)d_in[6];
  float* out = (float*)d_out;

  const int N = in_sizes[0] / 128;
  const int E = in_sizes[2];
  const int* dstp = src + E;

  const int NB = (N + 63) >> 6;  // buckets of 64 nodes
  const int chunk = (E + NBLK - 1) / NBLK;

  // layout (4B units): dinv[oN] | rowst[oN] | bstart[2048] | partials[32768]
  //   | recs[E] | xb/bkt[max(2E, N*64)] | xab[N*64] (blkhist aliases) | w0f | w1f
  float* ws = (float*)d_ws;
  const size_t oN = ((size_t)N + 255) & ~(size_t)255;
  float* dinv = ws;
  int* rowst = (int*)(ws + oN);
  int* bstart = rowst + oN;
  int* partials = bstart + 2048;
  unsigned int* recs = (unsigned int*)(partials + 32768);
  unsigned int* xb = recs + E;  // aliases bkt
  uint2* bkt = (uint2*)xb;
  const size_t xb_units = ((size_t)2 * E > (size_t)N * 64) ? (size_t)2 * E : (size_t)N * 64;
  unsigned int* xab = xb + xb_units;
  int* blkhist = (int*)xab;  // alias: blkhist dead before xab is written
  unsigned short* w0f = (unsigned short*)(xab + (size_t)N * 64);
  unsigned short* w1f = w0f + 16384;
  unsigned int* r2b = xb;  // xb dead after gather_l1 passes

  const int nbE = (E + 255) / 256;
  const int nblkB = (NB + 255) / 256;

  // ---- CSR build via bucket sort (no global atomics) ----
  bucket_hist<<<NBLK, 256, NB * 4, stream>>>(dstp, blkhist, NB, E, chunk);
  col_part<<<dim3(nblkB, GB), 256, 0, stream>>>(blkhist, partials, NB);
  col_scan16<<<nblkB, 256, 0, stream>>>(partials, bstart, NB);
  col_apply<<<dim3(nblkB, GB), 256, 0, stream>>>(blkhist, partials, NB);
  scan_single<<<1, 256, 0, stream>>>(bstart, NB);
  bucket_scatter<<<NBLK, 256, NB * 4, stream>>>(src, dstp, ew, blkhist, bstart, bkt, NB,
                                                E, chunk);
  bucket_finalize<<<NB, 256, 0, stream>>>(bkt, bstart, recs, rowst, dinv, NB, N, E);
  fold_dinv<<<nbE, 256, 0, stream>>>(recs, dinv, E);

  // ---- weights + features to bf16 ----
  pack_wfrag<<<64, 256, 0, stream>>>(W0, w0f, 128, 16384);
  pack_wfrag<<<32, 256, 0, stream>>>(W1, w1f, 64, 8192);
  to_bf16_8<<<(N * 16 + 255) / 256, 256, 0, stream>>>(x, (unsigned short*)xb, N * 16);

  // ---- layer 1 aggregate: 8 column passes (pool 3.2 MB each) ----
  const int gpb = (N * 2 + 255) / 256;
  for (int p = 0; p < 8; ++p)
    gather_l1_pass<<<gpb, 256, 0, stream>>>((const uint4*)xb, recs, rowst, dinv,
                                            (uint4*)xab, N, p * 2);

  // ---- fused MFMA MLP ----
  fused_mlp_mfma<<<(N + 63) / 64, 256, 0, stream>>>((const unsigned short*)xab, w0f, b0,
                                                    w1f, (unsigned short*)r2b, N);

  // ---- layer 2 aggregate: 4 column passes + bias + sigmoid ----
  for (int p = 0; p < 4; ++p)
    gather_l2_pass<<<gpb, 256, 0, stream>>>((const uint4*)r2b, recs, rowst, dinv, b1,
                                            out, N, p * 2);
}

// Round 13
// 310.491 us; speedup vs baseline: 2.7181x; 2.7181x over previous
//
#include <hip/hip_runtime.h>
#include <math.h>

typedef __attribute__((ext_vector_type(8))) short bf16x8;
typedef __attribute__((ext_vector_type(4))) float f32x4;

#define NBLK 1024   // scatter/hist blocks (4 blocks/CU)
#define GB   16     // block-groups for column prefix
#define BPG  (NBLK / GB)

// ---------------- bf16 helpers (RNE) ----------------

__device__ __forceinline__ unsigned short f2b(float f) {
  unsigned u = __float_as_uint(f);
  unsigned r = u + 0x7fffu + ((u >> 16) & 1u);
  return (unsigned short)(r >> 16);
}
__device__ __forceinline__ float b2f_lo(unsigned v) {
  return __uint_as_float(v << 16);
}
__device__ __forceinline__ float b2f_hi(unsigned v) {
  return __uint_as_float(v & 0xffff0000u);
}

// ================= bucket-sort CSR build (no global atomics) =================
// bucket k covers dst in [k*256, k*256+256): ~8-edge runs per (block,bucket)
// -> bkt writes land in whole 64B lines (write-amp fix vs 64-node buckets).

__global__ __launch_bounds__(256) void bucket_hist(const int* __restrict__ dst,
                                                   int* __restrict__ blkhist,
                                                   int NB, int E, int chunk) {
  extern __shared__ int sm_hist[];
  for (int i = threadIdx.x; i < NB; i += 256) sm_hist[i] = 0;
  __syncthreads();
  const int b = blockIdx.x;
  const int beg = b * chunk;
  const int end = min(E, beg + chunk);
  int j = beg + threadIdx.x;
  for (; j + 768 < end; j += 1024) {  // 4 independent loads in flight
    const int d0 = dst[j], d1 = dst[j + 256], d2 = dst[j + 512], d3 = dst[j + 768];
    atomicAdd(&sm_hist[d0 >> 8], 1);
    atomicAdd(&sm_hist[d1 >> 8], 1);
    atomicAdd(&sm_hist[d2 >> 8], 1);
    atomicAdd(&sm_hist[d3 >> 8], 1);
  }
  for (; j < end; j += 256) atomicAdd(&sm_hist[dst[j] >> 8], 1);
  __syncthreads();
  for (int i = threadIdx.x; i < NB; i += 256) blkhist[(long)b * NB + i] = sm_hist[i];
}

// ---- 3-phase coalesced column prefix over blkhist[b][k] ----
__global__ __launch_bounds__(256) void col_part(const int* __restrict__ blkhist,
                                                int* __restrict__ partials, int NB) {
  const int k = blockIdx.x * 256 + threadIdx.x;
  const int g = blockIdx.y;
  if (k >= NB) return;
  const long base = (long)g * BPG * NB + k;
  int sum = 0;
  int i = 0;
  for (; i + 4 <= BPG; i += 4) {
    const int t0 = blkhist[base + (long)(i + 0) * NB];
    const int t1 = blkhist[base + (long)(i + 1) * NB];
    const int t2 = blkhist[base + (long)(i + 2) * NB];
    const int t3 = blkhist[base + (long)(i + 3) * NB];
    sum += t0 + t1 + t2 + t3;
  }
  for (; i < BPG; ++i) sum += blkhist[base + (long)i * NB];
  partials[(long)g * NB + k] = sum;
}

__global__ __launch_bounds__(256) void col_scan16(int* __restrict__ partials,
                                                  int* __restrict__ bstart, int NB) {
  const int k = blockIdx.x * 256 + threadIdx.x;
  if (k >= NB) return;
  int run = 0;
#pragma unroll
  for (int g = 0; g < GB; ++g) {
    const int t = partials[(long)g * NB + k];
    partials[(long)g * NB + k] = run;
    run += t;
  }
  bstart[k] = run;
}

__global__ __launch_bounds__(256) void col_apply(int* __restrict__ blkhist,
                                                 const int* __restrict__ partials,
                                                 int NB) {
  const int k = blockIdx.x * 256 + threadIdx.x;
  const int g = blockIdx.y;
  if (k >= NB) return;
  const long base = (long)g * BPG * NB + k;
  int run = partials[(long)g * NB + k];
  int i = 0;
  for (; i + 4 <= BPG; i += 4) {
    const int t0 = blkhist[base + (long)(i + 0) * NB];
    const int t1 = blkhist[base + (long)(i + 1) * NB];
    const int t2 = blkhist[base + (long)(i + 2) * NB];
    const int t3 = blkhist[base + (long)(i + 3) * NB];
    blkhist[base + (long)(i + 0) * NB] = run; run += t0;
    blkhist[base + (long)(i + 1) * NB] = run; run += t1;
    blkhist[base + (long)(i + 2) * NB] = run; run += t2;
    blkhist[base + (long)(i + 3) * NB] = run; run += t3;
  }
  for (; i < BPG; ++i) {
    const int t = blkhist[base + (long)i * NB];
    blkhist[base + (long)i * NB] = run;
    run += t;
  }
}

// single-block in-place exclusive scan over cr[0..n); cr[n] = total.
__global__ __launch_bounds__(256) void scan_single(int* __restrict__ cr, int n) {
  __shared__ int sm[256];
  __shared__ int sbase;
  if (threadIdx.x == 0) sbase = 0;
  __syncthreads();
  for (int c0 = 0; c0 < n; c0 += 256) {
    const int i = c0 + threadIdx.x;
    const int v = (i < n) ? cr[i] : 0;
    sm[threadIdx.x] = v;
    __syncthreads();
    for (int off = 1; off < 256; off <<= 1) {
      int a = (threadIdx.x >= off) ? sm[threadIdx.x - off] : 0;
      __syncthreads();
      sm[threadIdx.x] += a;
      __syncthreads();
    }
    const int b = sbase;
    const int tot = sm[255];
    if (i < n) cr[i] = b + sm[threadIdx.x] - v;
    __syncthreads();
    if (threadIdx.x == 0) sbase = b + tot;
    __syncthreads();
  }
  if (threadIdx.x == 0) cr[n] = sbase;
}

// scatter edges into bucket ranges; positions via LDS cursors (no global atomics)
__global__ __launch_bounds__(256) void bucket_scatter(const int* __restrict__ src,
                                                      const int* __restrict__ dst,
                                                      const float* __restrict__ ew,
                                                      const int* __restrict__ blkhist,
                                                      const int* __restrict__ bstart,
                                                      uint2* __restrict__ bkt, int NB,
                                                      int E, int chunk) {
  extern __shared__ int sm_cur[];
  const int b = blockIdx.x;
  for (int i = threadIdx.x; i < NB; i += 256)
    sm_cur[i] = blkhist[(long)b * NB + i] + bstart[i];
  __syncthreads();
  const int beg = b * chunk;
  const int end = min(E, beg + chunk);
  int j = beg + threadIdx.x;
  for (; j + 768 < end; j += 1024) {  // 4 edges in flight
    const int d0 = dst[j], d1 = dst[j + 256], d2 = dst[j + 512], d3 = dst[j + 768];
    const int s0 = src[j], s1 = src[j + 256], s2 = src[j + 512], s3 = src[j + 768];
    const float e0 = ew[j], e1 = ew[j + 256], e2 = ew[j + 512], e3 = ew[j + 768];
    int q0 = (int)(e0 * 32767.f + 0.5f); q0 = (q0 < 0) ? 0 : ((q0 > 32767) ? 32767 : q0);
    int q1 = (int)(e1 * 32767.f + 0.5f); q1 = (q1 < 0) ? 0 : ((q1 > 32767) ? 32767 : q1);
    int q2 = (int)(e2 * 32767.f + 0.5f); q2 = (q2 < 0) ? 0 : ((q2 > 32767) ? 32767 : q2);
    int q3 = (int)(e3 * 32767.f + 0.5f); q3 = (q3 < 0) ? 0 : ((q3 > 32767) ? 32767 : q3);
    const int p0 = atomicAdd(&sm_cur[d0 >> 8], 1);
    bkt[p0] = make_uint2(((unsigned)s0 << 15) | (unsigned)q0, (unsigned)(d0 & 255));
    const int p1 = atomicAdd(&sm_cur[d1 >> 8], 1);
    bkt[p1] = make_uint2(((unsigned)s1 << 15) | (unsigned)q1, (unsigned)(d1 & 255));
    const int p2 = atomicAdd(&sm_cur[d2 >> 8], 1);
    bkt[p2] = make_uint2(((unsigned)s2 << 15) | (unsigned)q2, (unsigned)(d2 & 255));
    const int p3 = atomicAdd(&sm_cur[d3 >> 8], 1);
    bkt[p3] = make_uint2(((unsigned)s3 << 15) | (unsigned)q3, (unsigned)(d3 & 255));
  }
  for (; j < end; j += 256) {
    const int d = dst[j];
    int q = (int)(ew[j] * 32767.f + 0.5f);
    q = (q < 0) ? 0 : ((q > 32767) ? 32767 : q);
    const unsigned rec = ((unsigned)src[j] << 15) | (unsigned)q;
    const int pos = atomicAdd(&sm_cur[d >> 8], 1);
    bkt[pos] = make_uint2(rec, (unsigned)(d & 255));
  }
}

// per-bucket (256 nodes): local CSR + row_start + deg/dinv, then scatter recs
__global__ __launch_bounds__(256) void bucket_finalize(const uint2* __restrict__ bkt,
                                                       const int* __restrict__ bstart,
                                                       unsigned* __restrict__ recs,
                                                       int* __restrict__ row_start,
                                                       float* __restrict__ dinv, int NB,
                                                       int N, int E) {
  __shared__ int hist[256], qs[256], cur[256], lstart[256];
  const int k = blockIdx.x;
  const int t = threadIdx.x;
  hist[t] = 0;
  qs[t] = 0;
  __syncthreads();
  const int beg = bstart[k], end = bstart[k + 1];
  for (int j = beg + t; j < end; j += 256) {
    const uint2 v = bkt[j];
    atomicAdd(&hist[v.y], 1);
    atomicAdd(&qs[v.y], (int)(v.x & 32767u));
  }
  __syncthreads();
  if (t == 0) {
    int run = 0;
    for (int i = 0; i < 256; ++i) { lstart[i] = run; run += hist[i]; }
  }
  __syncthreads();
  cur[t] = lstart[t];
  const int node = k * 256 + t;
  if (node < N) {
    row_start[node] = beg + lstart[t];
    dinv[node] = rsqrtf((float)qs[t] * (1.f / 32767.f) + 2.0f);  // +2 self-loop
  }
  if (k == NB - 1 && t == 0) row_start[N] = E;
  __syncthreads();
  for (int j = beg + t; j < end; j += 256) {
    const uint2 v = bkt[j];
    const int off = atomicAdd(&cur[v.y], 1);  // LDS atomic
    recs[beg + off] = v.x;
  }
}

// ---------------- fold dinv[src] into records: q' = q15( ew*dinv[src] / 0.75 ) ----------------

__global__ __launch_bounds__(256) void fold_dinv(unsigned int* __restrict__ recs,
                                                 const float* __restrict__ dinv, int E) {
  int i = blockIdx.x * 256 + threadIdx.x;
  if (i >= E) return;
  const unsigned rec = recs[i];
  const int s = rec >> 15;
  const float v = (float)(rec & 32767u) * (1.f / 32767.f) * dinv[s];
  int q = (int)(v * (32767.f / 0.75f) + 0.5f);
  q = (q > 32767) ? 32767 : q;
  recs[i] = ((unsigned)s << 15) | (unsigned)q;
}

// ---------------- x (f32) -> xb (bf16), 8 elements/thread ----------------

__global__ __launch_bounds__(256) void to_bf16_8(const float* __restrict__ x,
                                                 unsigned short* __restrict__ xb,
                                                 int n8) {
  int i = blockIdx.x * 256 + threadIdx.x;
  if (i >= n8) return;
  const float4 a = *(const float4*)&x[(long)i * 8];
  const float4 b = *(const float4*)&x[(long)i * 8 + 4];
  uint4 o;
  o.x = (unsigned)f2b(a.x) | ((unsigned)f2b(a.y) << 16);
  o.y = (unsigned)f2b(a.z) | ((unsigned)f2b(a.w) << 16);
  o.z = (unsigned)f2b(b.x) | ((unsigned)f2b(b.y) << 16);
  o.w = (unsigned)f2b(b.z) | ((unsigned)f2b(b.w) << 16);
  *(uint4*)&xb[(long)i * 8] = o;
}

// pack W (f32, row-major [K][C]) into per-lane MFMA B-fragments (bf16)
__global__ __launch_bounds__(256) void pack_wfrag(const float* __restrict__ W,
                                                  unsigned short* __restrict__ frag,
                                                  int C, int total) {
  int i = blockIdx.x * 256 + threadIdx.x;
  if (i >= total) return;
  const int e = i & 7;
  const int lane = (i >> 3) & 63;
  const int t = i >> 9;  // ct*(K/32) + kk, K/32 == 4
  const int kk = t & 3;
  const int ct = t >> 2;
  const int k = kk * 32 + (lane >> 4) * 8 + e;
  const int c = ct * 16 + (lane & 15);
  frag[i] = f2b(W[(long)k * C + c]);
}

// ---------------- layer-1 gather, column-half pass: 8 lanes/node, uint4, 8x unrolled ----------------
// (full-line 128B half-rows; round-11 proven form — column-splitting beyond this
//  breaks line locality, see round-12 post-mortem)

__global__ __launch_bounds__(256) void gather_l1_half(const uint4* __restrict__ xb4,
                                                      const unsigned int* __restrict__ recs,
                                                      const int* __restrict__ row_start,
                                                      const float* __restrict__ dinv,
                                                      uint4* __restrict__ xab4, int N,
                                                      int half) {
  const int t = blockIdx.x * 256 + threadIdx.x;
  const int d = t >> 3;
  if (d >= N) return;
  const int jl = (t & 7) + half * 8;
  const int beg = row_start[d], end = row_start[d + 1];
  const float dd = dinv[d];
  constexpr float S = 0.75f / 32767.f;
  const uint4 sv = xb4[(long)d * 16 + jl];
  const float sl = 2.f * dd * dd;
  float aca[8], acb[8];
  aca[0] = b2f_lo(sv.x) * sl; aca[1] = b2f_hi(sv.x) * sl;
  aca[2] = b2f_lo(sv.y) * sl; aca[3] = b2f_hi(sv.y) * sl;
  aca[4] = b2f_lo(sv.z) * sl; aca[5] = b2f_hi(sv.z) * sl;
  aca[6] = b2f_lo(sv.w) * sl; aca[7] = b2f_hi(sv.w) * sl;
#pragma unroll
  for (int u = 0; u < 8; ++u) acb[u] = 0.f;
  int j = beg;
  for (; j + 8 <= end; j += 8) {
    unsigned rr[8];
    uint4 vv[8];
#pragma unroll
    for (int u = 0; u < 8; ++u) rr[u] = recs[j + u];
#pragma unroll
    for (int u = 0; u < 8; ++u) vv[u] = xb4[(long)(rr[u] >> 15) * 16 + jl];
#pragma unroll
    for (int u = 0; u < 8; ++u) {
      const float cf = (float)(rr[u] & 32767u) * S * dd;
      float* ac = (u & 1) ? acb : aca;
      ac[0] = fmaf(cf, b2f_lo(vv[u].x), ac[0]);
      ac[1] = fmaf(cf, b2f_hi(vv[u].x), ac[1]);
      ac[2] = fmaf(cf, b2f_lo(vv[u].y), ac[2]);
      ac[3] = fmaf(cf, b2f_hi(vv[u].y), ac[3]);
      ac[4] = fmaf(cf, b2f_lo(vv[u].z), ac[4]);
      ac[5] = fmaf(cf, b2f_hi(vv[u].z), ac[5]);
      ac[6] = fmaf(cf, b2f_lo(vv[u].w), ac[6]);
      ac[7] = fmaf(cf, b2f_hi(vv[u].w), ac[7]);
    }
  }
  for (; j < end; ++j) {
    const unsigned rec = recs[j];
    const uint4 v = xb4[(long)(rec >> 15) * 16 + jl];
    const float cf = (float)(rec & 32767u) * S * dd;
    aca[0] = fmaf(cf, b2f_lo(v.x), aca[0]);
    aca[1] = fmaf(cf, b2f_hi(v.x), aca[1]);
    aca[2] = fmaf(cf, b2f_lo(v.y), aca[2]);
    aca[3] = fmaf(cf, b2f_hi(v.y), aca[3]);
    aca[4] = fmaf(cf, b2f_lo(v.z), aca[4]);
    aca[5] = fmaf(cf, b2f_hi(v.z), aca[5]);
    aca[6] = fmaf(cf, b2f_lo(v.w), aca[6]);
    aca[7] = fmaf(cf, b2f_hi(v.w), aca[7]);
  }
#pragma unroll
  for (int u = 0; u < 8; ++u) aca[u] += acb[u];
  uint4 o;
  o.x = (unsigned)f2b(aca[0]) | ((unsigned)f2b(aca[1]) << 16);
  o.y = (unsigned)f2b(aca[2]) | ((unsigned)f2b(aca[3]) << 16);
  o.z = (unsigned)f2b(aca[4]) | ((unsigned)f2b(aca[5]) << 16);
  o.w = (unsigned)f2b(aca[6]) | ((unsigned)f2b(aca[7]) << 16);
  xab4[(long)d * 16 + jl] = o;
}

// ---------------- fused MLP via MFMA (verified layout, unchanged) ----------------

__global__ __launch_bounds__(256) void fused_mlp_mfma(
    const unsigned short* __restrict__ xab, const unsigned short* __restrict__ w0f,
    const float* __restrict__ b0, const unsigned short* __restrict__ w1f,
    unsigned short* __restrict__ r2b, int N) {
  __shared__ unsigned short Hl[4][16][136];
  const int tid = threadIdx.x;
  const int w = tid >> 6, l = tid & 63;
  const int lr = l & 15, lg = l >> 4;
  const int row0 = blockIdx.x * 64 + w * 16;

  int arow = row0 + lr;
  if (arow >= N) arow = N - 1;
  const unsigned short* ap = xab + (long)arow * 128 + lg * 8;
  const bf16x8 a0 = *(const bf16x8*)(ap);
  const bf16x8 a1 = *(const bf16x8*)(ap + 32);
  const bf16x8 a2 = *(const bf16x8*)(ap + 64);
  const bf16x8 a3 = *(const bf16x8*)(ap + 96);

  for (int ct = 0; ct < 8; ++ct) {
    const unsigned short* bp = w0f + ct * 2048 + l * 8;
    f32x4 acc = {0.f, 0.f, 0.f, 0.f};
    acc = __builtin_amdgcn_mfma_f32_16x16x32_bf16(a0, *(const bf16x8*)(bp), acc, 0, 0, 0);
    acc = __builtin_amdgcn_mfma_f32_16x16x32_bf16(a1, *(const bf16x8*)(bp + 512), acc, 0, 0, 0);
    acc = __builtin_amdgcn_mfma_f32_16x16x32_bf16(a2, *(const bf16x8*)(bp + 1024), acc, 0, 0, 0);
    acc = __builtin_amdgcn_mfma_f32_16x16x32_bf16(a3, *(const bf16x8*)(bp + 1536), acc, 0, 0, 0);
    const float bv = b0[ct * 16 + lr];
#pragma unroll
    for (int r = 0; r < 4; ++r) {
      Hl[w][lg * 4 + r][ct * 16 + lr] = f2b(fmaxf(acc[r] + bv, 0.f));
    }
  }

  const unsigned short* hp = &Hl[w][lr][lg * 8];
  const bf16x8 h0 = *(const bf16x8*)(hp);
  const bf16x8 h1 = *(const bf16x8*)(hp + 32);
  const bf16x8 h2 = *(const bf16x8*)(hp + 64);
  const bf16x8 h3 = *(const bf16x8*)(hp + 96);

  for (int ct = 0; ct < 4; ++ct) {
    const unsigned short* bp = w1f + ct * 2048 + l * 8;
    f32x4 acc = {0.f, 0.f, 0.f, 0.f};
    acc = __builtin_amdgcn_mfma_f32_16x16x32_bf16(h0, *(const bf16x8*)(bp), acc, 0, 0, 0);
    acc = __builtin_amdgcn_mfma_f32_16x16x32_bf16(h1, *(const bf16x8*)(bp + 512), acc, 0, 0, 0);
    acc = __builtin_amdgcn_mfma_f32_16x16x32_bf16(h2, *(const bf16x8*)(bp + 1024), acc, 0, 0, 0);
    acc = __builtin_amdgcn_mfma_f32_16x16x32_bf16(h3, *(const bf16x8*)(bp + 1536), acc, 0, 0, 0);
#pragma unroll
    for (int r = 0; r < 4; ++r) {
      const int orow = row0 + lg * 4 + r;
      if (orow < N) r2b[(long)orow * 64 + ct * 16 + lr] = f2b(acc[r]);
    }
  }
}

// ---------------- layer-2 gather + b1 + sigmoid: 8 lanes/node, uint4, 8x unrolled ----------------

__global__ __launch_bounds__(256) void gather_l2(const uint4* __restrict__ r2b4,
                                                 const unsigned int* __restrict__ recs,
                                                 const int* __restrict__ row_start,
                                                 const float* __restrict__ dinv,
                                                 const float* __restrict__ b1,
                                                 float* __restrict__ out, int N) {
  const int t = blockIdx.x * 256 + threadIdx.x;
  const int d = t >> 3;
  if (d >= N) return;
  const int jl = t & 7;
  const int beg = row_start[d], end = row_start[d + 1];
  const float dd = dinv[d];
  constexpr float S = 0.75f / 32767.f;
  const uint4 sv = r2b4[(long)d * 8 + jl];
  const float sl = 2.f * dd * dd;
  float aca[8], acb[8];
  aca[0] = b2f_lo(sv.x) * sl; aca[1] = b2f_hi(sv.x) * sl;
  aca[2] = b2f_lo(sv.y) * sl; aca[3] = b2f_hi(sv.y) * sl;
  aca[4] = b2f_lo(sv.z) * sl; aca[5] = b2f_hi(sv.z) * sl;
  aca[6] = b2f_lo(sv.w) * sl; aca[7] = b2f_hi(sv.w) * sl;
#pragma unroll
  for (int u = 0; u < 8; ++u) acb[u] = 0.f;
  int j = beg;
  for (; j + 8 <= end; j += 8) {
    unsigned rr[8];
    uint4 vv[8];
#pragma unroll
    for (int u = 0; u < 8; ++u) rr[u] = recs[j + u];
#pragma unroll
    for (int u = 0; u < 8; ++u) vv[u] = r2b4[(long)(rr[u] >> 15) * 8 + jl];
#pragma unroll
    for (int u = 0; u < 8; ++u) {
      const float cf = (float)(rr[u] & 32767u) * S * dd;
      float* ac = (u & 1) ? acb : aca;
      ac[0] = fmaf(cf, b2f_lo(vv[u].x), ac[0]);
      ac[1] = fmaf(cf, b2f_hi(vv[u].x), ac[1]);
      ac[2] = fmaf(cf, b2f_lo(vv[u].y), ac[2]);
      ac[3] = fmaf(cf, b2f_hi(vv[u].y), ac[3]);
      ac[4] = fmaf(cf, b2f_lo(vv[u].z), ac[4]);
      ac[5] = fmaf(cf, b2f_hi(vv[u].z), ac[5]);
      ac[6] = fmaf(cf, b2f_lo(vv[u].w), ac[6]);
      ac[7] = fmaf(cf, b2f_hi(vv[u].w), ac[7]);
    }
  }
  for (; j < end; ++j) {
    const unsigned rec = recs[j];
    const uint4 v = r2b4[(long)(rec >> 15) * 8 + jl];
    const float cf = (float)(rec & 32767u) * S * dd;
    aca[0] = fmaf(cf, b2f_lo(v.x), aca[0]);
    aca[1] = fmaf(cf, b2f_hi(v.x), aca[1]);
    aca[2] = fmaf(cf, b2f_lo(v.y), aca[2]);
    aca[3] = fmaf(cf, b2f_hi(v.y), aca[3]);
    aca[4] = fmaf(cf, b2f_lo(v.z), aca[4]);
    aca[5] = fmaf(cf, b2f_hi(v.z), aca[5]);
    aca[6] = fmaf(cf, b2f_lo(v.w), aca[6]);
    aca[7] = fmaf(cf, b2f_hi(v.w), aca[7]);
  }
#pragma unroll
  for (int u = 0; u < 8; ++u) aca[u] += acb[u];
  const int c = jl * 8;
  const float4 ba = *(const float4*)&b1[c];
  const float4 bb = *(const float4*)&b1[c + 4];
  float4 o1, o2;
  o1.x = 1.f / (1.f + __expf(-(aca[0] + ba.x)));
  o1.y = 1.f / (1.f + __expf(-(aca[1] + ba.y)));
  o1.z = 1.f / (1.f + __expf(-(aca[2] + ba.z)));
  o1.w = 1.f / (1.f + __expf(-(aca[3] + ba.w)));
  o2.x = 1.f / (1.f + __expf(-(aca[4] + bb.x)));
  o2.y = 1.f / (1.f + __expf(-(aca[5] + bb.y)));
  o2.z = 1.f / (1.f + __expf(-(aca[6] + bb.z)));
  o2.w = 1.f / (1.f + __expf(-(aca[7] + bb.w)));
  *(float4*)&out[(long)d * 64 + c] = o1;
  *(float4*)&out[(long)d * 64 + c + 4] = o2;
}

// ---------------- launch ----------------
// out = sigmoid( Ahat @ (relu((Ahat @ x) @ W0 + b0) @ W1) + b1 ),
// Ahat = D^-1/2 (A+2I) D^-1/2, using Ahat(x W0) == (Ahat x) W0.
// CSR via LDS-histogram bucket sort (zero global atomics), 256-node buckets
// (scatter write-amp fix), NBLK=1024, 3-phase coalesced column prefix;
// full-line gathers (round-12 column-split reverted: line locality > pool size);
// MLP on matrix cores. Workspace ~65 MB (< 71.6 MB proven available).

extern "C" void kernel_launch(void* const* d_in, const int* in_sizes, int n_in,
                              void* d_out, int out_size, void* d_ws, size_t ws_size,
                              hipStream_t stream) {
  const float* x  = (const float*)d_in[0];
  const int* src  = (const int*)d_in[1];
  const float* ew = (const float*)d_in[2];
  const float* W0 = (const float*)d_in[3];
  const float* b0 = (const float*)d_in[4];
  const float* W1 = (const float*)d_in[5];
  const float* b1 = (const float*)d_in[6];
  float* out = (float*)d_out;

  const int N = in_sizes[0] / 128;
  const int E = in_sizes[2];
  const int* dstp = src + E;

  const int NB = (N + 255) >> 8;  // buckets of 256 nodes
  const int chunk = (E + NBLK - 1) / NBLK;

  // layout (4B units): dinv[oN] | rowst[oN] | bstart[2048] | partials[32768]
  //   | recs[E] | xb/bkt[max(2E, N*64)] | xab[N*64] (blkhist aliases) | w0f | w1f
  float* ws = (float*)d_ws;
  const size_t oN = ((size_t)N + 255) & ~(size_t)255;
  float* dinv = ws;
  int* rowst = (int*)(ws + oN);
  int* bstart = rowst + oN;
  int* partials = bstart + 2048;
  unsigned int* recs = (unsigned int*)(partials + 32768);
  unsigned int* xb = recs + E;  // aliases bkt
  uint2* bkt = (uint2*)xb;
  const size_t xb_units = ((size_t)2 * E > (size_t)N * 64) ? (size_t)2 * E : (size_t)N * 64;
  unsigned int* xab = xb + xb_units;
  int* blkhist = (int*)xab;  // alias: blkhist dead before xab is written
  unsigned short* w0f = (unsigned short*)(xab + (size_t)N * 64);
  unsigned short* w1f = w0f + 16384;
  unsigned int* r2b = xb;  // xb dead after gather_l1 passes

  const int nbE = (E + 255) / 256;
  const int nblkB = (NB + 255) / 256;

  // ---- CSR build via bucket sort (no global atomics) ----
  bucket_hist<<<NBLK, 256, NB * 4, stream>>>(dstp, blkhist, NB, E, chunk);
  col_part<<<dim3(nblkB, GB), 256, 0, stream>>>(blkhist, partials, NB);
  col_scan16<<<nblkB, 256, 0, stream>>>(partials, bstart, NB);
  col_apply<<<dim3(nblkB, GB), 256, 0, stream>>>(blkhist, partials, NB);
  scan_single<<<1, 256, 0, stream>>>(bstart, NB);
  bucket_scatter<<<NBLK, 256, NB * 4, stream>>>(src, dstp, ew, blkhist, bstart, bkt, NB,
                                                E, chunk);
  bucket_finalize<<<NB, 256, 0, stream>>>(bkt, bstart, recs, rowst, dinv, NB, N, E);
  fold_dinv<<<nbE, 256, 0, stream>>>(recs, dinv, E);

  // ---- weights + features to bf16 ----
  pack_wfrag<<<64, 256, 0, stream>>>(W0, w0f, 128, 16384);
  pack_wfrag<<<32, 256, 0, stream>>>(W1, w1f, 64, 8192);
  to_bf16_8<<<(N * 16 + 255) / 256, 256, 0, stream>>>(x, (unsigned short*)xb, N * 16);

  // ---- layer 1 aggregate (two column-half passes, full-line reads) ----
  const int gl1b = (N * 8 + 255) / 256;
  gather_l1_half<<<gl1b, 256, 0, stream>>>((const uint4*)xb, recs, rowst, dinv,
                                           (uint4*)xab, N, 0);
  gather_l1_half<<<gl1b, 256, 0, stream>>>((const uint4*)xb, recs, rowst, dinv,
                                           (uint4*)xab, N, 1);

  // ---- fused MFMA MLP ; layer 2 aggregate + sigmoid ----
  fused_mlp_mfma<<<(N + 63) / 64, 256, 0, stream>>>((const unsigned short*)xab, w0f, b0,
                                                    w1f, (unsigned short*)r2b, N);
  gather_l2<<<(N * 8 + 255) / 256, 256, 0, stream>>>((const uint4*)r2b, recs, rowst, dinv,
                                                     b1, out, N);
}